// Round 1
// baseline (164.408 us; speedup 1.0000x reference)
//
#include <hip/hip_runtime.h>
#include <math.h>

// Problem constants (B=128, C=2, H=W=256)
#define HM_H 256
#define HM_W 256
#define HM_N (HM_H * HM_W)     // 65536 pixels per heatmap
#define N_HM 256               // B*C heatmaps
#define NTHR 1024
#define NWAVES (NTHR / 64)
#define ITERS (HM_N / 4 / NTHR) // 16 float4 iterations per thread

// ws layout (floats): px[256] | py[256] | jsd[256] | tx[256] | ty[256]

__global__ __launch_bounds__(NTHR) void heatmap_kernel(
    const float* __restrict__ inp, const float* __restrict__ tgt,
    float* __restrict__ ws)
{
    const int hm = blockIdx.x;
    const size_t base = (size_t)hm * HM_N;
    const float4* __restrict__ in4 = (const float4*)(inp + base);
    const float4* __restrict__ tg4 = (const float4*)(tgt + base);
    const int tid = threadIdx.x;

    // ---------------- pass 1: online max+sumexp(input), argmax(target) ----
    float mval = -INFINITY, sacc = 0.0f;
    float bval = -INFINITY;
    int   bidx = HM_N; // first-occurrence argmax: strict > keeps earliest
#pragma unroll
    for (int it = 0; it < ITERS; ++it) {
        const int v = it * NTHR + tid;       // float4 index
        const float4 x = in4[v];
        const float4 t = tg4[v];
        const float lm = fmaxf(fmaxf(x.x, x.y), fmaxf(x.z, x.w));
        if (lm > mval) { sacc *= __expf(mval - lm); mval = lm; }
        sacc += __expf(x.x - mval) + __expf(x.y - mval)
              + __expf(x.z - mval) + __expf(x.w - mval);
        const int i0 = v * 4;
        if (t.x > bval) { bval = t.x; bidx = i0; }
        if (t.y > bval) { bval = t.y; bidx = i0 + 1; }
        if (t.z > bval) { bval = t.z; bidx = i0 + 2; }
        if (t.w > bval) { bval = t.w; bidx = i0 + 3; }
    }

    // wave (64-lane) butterfly reduce
#pragma unroll
    for (int off = 1; off < 64; off <<= 1) {
        const float m2 = __shfl_xor(mval, off);
        const float s2 = __shfl_xor(sacc, off);
        const float nm = fmaxf(mval, m2);
        sacc = sacc * __expf(mval - nm) + s2 * __expf(m2 - nm);
        mval = nm;
        const float bv2 = __shfl_xor(bval, off);
        const int   bi2 = __shfl_xor(bidx, off);
        if (bv2 > bval || (bv2 == bval && bi2 < bidx)) { bval = bv2; bidx = bi2; }
    }

    __shared__ float lm_[NWAVES], ls_[NWAVES], lbv_[NWAVES];
    __shared__ int   lbi_[NWAVES];
    __shared__ float s_max, s_invZ;
    __shared__ int   s_idx;
    const int wid = tid >> 6, lane = tid & 63;
    if (lane == 0) { lm_[wid] = mval; ls_[wid] = sacc; lbv_[wid] = bval; lbi_[wid] = bidx; }
    __syncthreads();
    if (tid == 0) {
        float M = lm_[0], S = ls_[0], BV = lbv_[0];
        int BI = lbi_[0];
        for (int i = 1; i < NWAVES; ++i) {
            const float m2 = lm_[i], s2 = ls_[i];
            const float nm = fmaxf(M, m2);
            S = S * __expf(M - nm) + s2 * __expf(m2 - nm);
            M = nm;
            if (lbv_[i] > BV || (lbv_[i] == BV && lbi_[i] < BI)) { BV = lbv_[i]; BI = lbi_[i]; }
        }
        s_max = M; s_invZ = 1.0f / S; s_idx = BI;
    }
    __syncthreads();
    const float gmax = s_max, ginvZ = s_invZ;

    // ---------------- pass 2: pred_x, pred_y, jsd --------------------------
    // coords: x[j] = (j+1-128)/256, y[i] = (i+1-128)/256
    float px = 0.0f, py = 0.0f, jsd = 0.0f;
    const float cscale = 1.0f / 256.0f;
#pragma unroll
    for (int it = 0; it < ITERS; ++it) {
        const int v = it * NTHR + tid;
        const float4 x = in4[v];
        const float4 t = tg4[v];
        const int i0 = v * 4;
        const float yh  = ((float)(i0 >> 8) + 1.0f - 128.0f) * cscale;
        const float xw0 = ((float)(i0 & 255) + 1.0f - 128.0f) * cscale;

        const float p0 = __expf(x.x - gmax) * ginvZ;
        const float p1 = __expf(x.y - gmax) * ginvZ;
        const float p2 = __expf(x.z - gmax) * ginvZ;
        const float p3 = __expf(x.w - gmax) * ginvZ;

        px += p0 * xw0 + p1 * (xw0 + cscale) + p2 * (xw0 + 2.0f * cscale)
            + p3 * (xw0 + 3.0f * cscale);
        py += (p0 + p1 + p2 + p3) * yh;

        const float m0 = 0.5f * (t.x + p0);
        const float m1 = 0.5f * (t.y + p1);
        const float m2 = 0.5f * (t.z + p2);
        const float m3 = 0.5f * (t.w + p3);
        jsd += m0 * (__logf(m0) - m0);
        jsd += m1 * (__logf(m1) - m1);
        jsd += m2 * (__logf(m2) - m2);
        jsd += m3 * (__logf(m3) - m3);
    }

    // sum-reduce px/py/jsd across the block
#pragma unroll
    for (int off = 1; off < 64; off <<= 1) {
        px  += __shfl_xor(px, off);
        py  += __shfl_xor(py, off);
        jsd += __shfl_xor(jsd, off);
    }
    __shared__ float lpx[NWAVES], lpy[NWAVES], ljs[NWAVES];
    if (lane == 0) { lpx[wid] = px; lpy[wid] = py; ljs[wid] = jsd; }
    __syncthreads();
    if (tid == 0) {
        float PX = 0.0f, PY = 0.0f, JS = 0.0f;
        for (int i = 0; i < NWAVES; ++i) { PX += lpx[i]; PY += lpy[i]; JS += ljs[i]; }
        ws[hm]           = PX;
        ws[N_HM + hm]    = PY;
        ws[2 * N_HM + hm] = JS * (1.0f / (float)HM_N);
        const int bi = s_idx;
        ws[3 * N_HM + hm] = ((float)(bi & 255) + 1.0f - 128.0f) * (1.0f / 256.0f);
        ws[4 * N_HM + hm] = ((float)(bi >> 8)  + 1.0f - 128.0f) * (1.0f / 256.0f);
    }
}

__global__ __launch_bounds__(256) void finalize_kernel(
    const float* __restrict__ ws, float* __restrict__ out)
{
    __shared__ float acc[256];
    const int t = threadIdx.x;
    const float* px  = ws;
    const float* py  = ws + N_HM;
    const float* jsd = ws + 2 * N_HM;
    const float* tx  = ws + 3 * N_HM;
    const float* ty  = ws + 4 * N_HM;

    const float ex = tx[t] - px[t];
    const float ey = ty[t] - py[t];
    float v = sqrtf(ex * ex + ey * ey) + jsd[t];

    if (t < 128) { // per-batch inter-landmark distance term (channels 0,1)
        const int a = 2 * t, b = 2 * t + 1;
        const float pdx = px[a] - px[b], pdy = py[a] - py[b];
        const float pd  = sqrtf(pdx * pdx + pdy * pdy);
        const float tdx = tx[a] - tx[b], tdy = ty[a] - ty[b];
        const float td  = sqrtf(tdx * tdx + tdy * tdy);
        v += fabsf(pd - td) / td;
    }
    acc[t] = v;
    __syncthreads();
#pragma unroll
    for (int off = 128; off > 0; off >>= 1) {
        if (t < off) acc[t] += acc[t + off];
        __syncthreads();
    }
    if (t == 0) out[0] = acc[0] * (1.0f / 128.0f);
}

extern "C" void kernel_launch(void* const* d_in, const int* in_sizes, int n_in,
                              void* d_out, int out_size, void* d_ws, size_t ws_size,
                              hipStream_t stream) {
    const float* inp = (const float*)d_in[0];
    const float* tgt = (const float*)d_in[1];
    float* out = (float*)d_out;
    float* ws  = (float*)d_ws;

    heatmap_kernel<<<N_HM, NTHR, 0, stream>>>(inp, tgt, ws);
    finalize_kernel<<<1, 256, 0, stream>>>(ws, out);
}

// Round 2
// 150.482 us; speedup vs baseline: 1.0925x; 1.0925x over previous
//
#include <hip/hip_runtime.h>
#include <math.h>

// Problem constants (B=128, C=2, H=W=256)
#define HM_H 256
#define HM_W 256
#define HM_N (HM_H * HM_W)      // 65536 pixels per heatmap
#define N_HM 256                // B*C heatmaps
#define PARTS 8                 // parts per heatmap
#define NPART (N_HM * PARTS)    // 2048 blocks
#define PIX_PART (HM_N / PARTS) // 8192 pixels per part
#define NTHR 256
#define F4T (PIX_PART / 4 / NTHR) // 8 float4 per thread

// ws layout (float offsets):
//   zpart [0,2048) | pxp [2048,4096) | pyp [4096,6144) | jsp [6144,8192)
//   packp (uint64) at float offset 8192 (byte 32768), 2048 entries (16 KB)
#define WS_Z   0
#define WS_PX  2048
#define WS_PY  4096
#define WS_JS  6144
#define WS_PK  8192   // float offset; cast to unsigned long long*

// ---------------- K1: per-part sum of exp(input) --------------------------
__global__ __launch_bounds__(NTHR, 8) void sumexp_kernel(
    const float* __restrict__ inp, float* __restrict__ ws)
{
    const int part = blockIdx.x;
    const float4* __restrict__ in4 =
        (const float4*)(inp + (size_t)part * PIX_PART);
    const int tid = threadIdx.x;

    float4 v[F4T];
#pragma unroll
    for (int i = 0; i < F4T; ++i) v[i] = in4[i * NTHR + tid];

    float s0 = 0.f, s1 = 0.f, s2 = 0.f, s3 = 0.f;
#pragma unroll
    for (int i = 0; i < F4T; ++i) {
        s0 += __expf(v[i].x); s1 += __expf(v[i].y);
        s2 += __expf(v[i].z); s3 += __expf(v[i].w);
    }
    float s = (s0 + s1) + (s2 + s3);
#pragma unroll
    for (int off = 1; off < 64; off <<= 1) s += __shfl_xor(s, off);

    __shared__ float ls[NTHR / 64];
    const int wid = tid >> 6, lane = tid & 63;
    if (lane == 0) ls[wid] = s;
    __syncthreads();
    if (tid == 0) ws[WS_Z + part] = (ls[0] + ls[1]) + (ls[2] + ls[3]);
}

// ---------------- K2: px, py, jsd, argmax(target) per part ----------------
__global__ __launch_bounds__(NTHR, 4) void main_kernel(
    const float* __restrict__ inp, const float* __restrict__ tgt,
    float* __restrict__ ws)
{
    const int part = blockIdx.x;
    const int hm = part >> 3;
    const int tid = threadIdx.x;

    float Z = 0.f;
#pragma unroll
    for (int i = 0; i < PARTS; ++i) Z += ws[WS_Z + hm * PARTS + i];
    const float invZ = 1.0f / Z;

    const size_t base = (size_t)part * PIX_PART;
    const float4* __restrict__ in4 = (const float4*)(inp + base);
    const float4* __restrict__ tg4 = (const float4*)(tgt + base);
    const int pix0 = (part & (PARTS - 1)) * PIX_PART; // pixel offset in heatmap

    const float cs = 1.0f / 256.0f;
    float px = 0.f, py = 0.f, jsd = 0.f;
    unsigned long long best = 0ull;

#pragma unroll
    for (int half = 0; half < 2; ++half) {
        float4 x[4], t[4];
#pragma unroll
        for (int i = 0; i < 4; ++i) {
            const int f4 = (half * 4 + i) * NTHR + tid;
            x[i] = in4[f4];
            t[i] = tg4[f4];
        }
#pragma unroll
        for (int i = 0; i < 4; ++i) {
            const int f4 = (half * 4 + i) * NTHR + tid;
            const int gp = pix0 + f4 * 4;           // pixel index in heatmap
            const float yh  = ((float)(gp >> 8) + 1.0f - 128.0f) * cs;
            const float xw0 = ((float)(gp & 255) + 1.0f - 128.0f) * cs;

            const float p0 = __expf(x[i].x) * invZ;
            const float p1 = __expf(x[i].y) * invZ;
            const float p2 = __expf(x[i].z) * invZ;
            const float p3 = __expf(x[i].w) * invZ;

            px += p0 * xw0 + p1 * (xw0 + cs) + p2 * (xw0 + 2.f * cs)
                + p3 * (xw0 + 3.f * cs);
            py += ((p0 + p1) + (p2 + p3)) * yh;

            const float m0 = 0.5f * (t[i].x + p0);
            const float m1 = 0.5f * (t[i].y + p1);
            const float m2 = 0.5f * (t[i].z + p2);
            const float m3 = 0.5f * (t[i].w + p3);
            jsd += m0 * (__logf(m0) - m0) + m1 * (__logf(m1) - m1)
                 + m2 * (__logf(m2) - m2) + m3 * (__logf(m3) - m3);

            // first-occurrence argmax: pack (valbits<<32)|(65535-idx), take max
            const unsigned long long k0 =
                ((unsigned long long)__float_as_uint(t[i].x) << 32) | (unsigned)(65535 - gp);
            const unsigned long long k1 =
                ((unsigned long long)__float_as_uint(t[i].y) << 32) | (unsigned)(65534 - gp);
            const unsigned long long k2 =
                ((unsigned long long)__float_as_uint(t[i].z) << 32) | (unsigned)(65533 - gp);
            const unsigned long long k3 =
                ((unsigned long long)__float_as_uint(t[i].w) << 32) | (unsigned)(65532 - gp);
            unsigned long long ka = k0 > k1 ? k0 : k1;
            unsigned long long kb = k2 > k3 ? k2 : k3;
            ka = ka > kb ? ka : kb;
            best = best > ka ? best : ka;
        }
    }

#pragma unroll
    for (int off = 1; off < 64; off <<= 1) {
        px  += __shfl_xor(px, off);
        py  += __shfl_xor(py, off);
        jsd += __shfl_xor(jsd, off);
        const unsigned long long b2 = __shfl_xor(best, off);
        best = best > b2 ? best : b2;
    }

    __shared__ float lpx[4], lpy[4], ljs[4];
    __shared__ unsigned long long lbk[4];
    const int wid = tid >> 6, lane = tid & 63;
    if (lane == 0) { lpx[wid] = px; lpy[wid] = py; ljs[wid] = jsd; lbk[wid] = best; }
    __syncthreads();
    if (tid == 0) {
        float PX = 0.f, PY = 0.f, JS = 0.f;
        unsigned long long BK = 0ull;
        for (int i = 0; i < 4; ++i) {
            PX += lpx[i]; PY += lpy[i]; JS += ljs[i];
            BK = BK > lbk[i] ? BK : lbk[i];
        }
        ws[WS_PX + part] = PX;
        ws[WS_PY + part] = PY;
        ws[WS_JS + part] = JS;
        ((unsigned long long*)(ws + WS_PK))[part] = BK;
    }
}

// ---------------- K3: finalize --------------------------------------------
__global__ __launch_bounds__(256) void finalize_kernel(
    const float* __restrict__ ws, float* __restrict__ out)
{
    const int t = threadIdx.x; // heatmap id
    const unsigned long long* packp = (const unsigned long long*)(ws + WS_PK);

    float PX = 0.f, PY = 0.f, JS = 0.f;
    unsigned long long BK = 0ull;
#pragma unroll
    for (int i = 0; i < PARTS; ++i) {
        PX += ws[WS_PX + t * PARTS + i];
        PY += ws[WS_PY + t * PARTS + i];
        JS += ws[WS_JS + t * PARTS + i];
        const unsigned long long b = packp[t * PARTS + i];
        BK = BK > b ? BK : b;
    }
    JS *= (1.0f / (float)HM_N);
    const int gp = 65535 - (int)(BK & 0xFFFFFFFFull);
    const float tx = ((float)(gp & 255) + 1.0f - 128.0f) * (1.0f / 256.0f);
    const float ty = ((float)(gp >> 8)  + 1.0f - 128.0f) * (1.0f / 256.0f);

    const float ex = tx - PX, ey = ty - PY;
    float v = sqrtf(ex * ex + ey * ey) + JS;

    __shared__ float sPX[256], sPY[256], sTX[256], sTY[256], acc[256];
    sPX[t] = PX; sPY[t] = PY; sTX[t] = tx; sTY[t] = ty;
    __syncthreads();

    if (t < 128) { // inter-landmark distance term (channels 0,1)
        const int a = 2 * t, b = 2 * t + 1;
        const float pdx = sPX[a] - sPX[b], pdy = sPY[a] - sPY[b];
        const float pd  = sqrtf(pdx * pdx + pdy * pdy);
        const float tdx = sTX[a] - sTX[b], tdy = sTY[a] - sTY[b];
        const float td  = sqrtf(tdx * tdx + tdy * tdy);
        v += fabsf(pd - td) / td;
    }
    acc[t] = v;
    __syncthreads();
#pragma unroll
    for (int off = 128; off > 0; off >>= 1) {
        if (t < off) acc[t] += acc[t + off];
        __syncthreads();
    }
    if (t == 0) out[0] = acc[0] * (1.0f / 128.0f);
}

extern "C" void kernel_launch(void* const* d_in, const int* in_sizes, int n_in,
                              void* d_out, int out_size, void* d_ws, size_t ws_size,
                              hipStream_t stream) {
    const float* inp = (const float*)d_in[0];
    const float* tgt = (const float*)d_in[1];
    float* out = (float*)d_out;
    float* ws  = (float*)d_ws;

    sumexp_kernel<<<NPART, NTHR, 0, stream>>>(inp, ws);
    main_kernel<<<NPART, NTHR, 0, stream>>>(inp, tgt, ws);
    finalize_kernel<<<1, 256, 0, stream>>>(ws, out);
}

// Round 7
// 147.425 us; speedup vs baseline: 1.1152x; 1.0207x over previous
//
#include <hip/hip_runtime.h>
#include <math.h>

// Problem constants (B=128, C=2, H=W=256)
#define HM_N 65536              // pixels per heatmap
#define N_HM 256                // B*C heatmaps
#define PARTS 8                 // parts per heatmap
#define NPART (N_HM * PARTS)    // 2048 blocks
#define PIX_PART (HM_N / PARTS) // 8192 pixels per part
#define NTHR 256                // 32 pixels per thread (8 float4)

// ws float offsets:
//   zpart[2048] | pxn[2048] | pyn[2048] | jsp[2048] | pack(ull)[2048]
#define WS_Z  0
#define WS_PX 2048
#define WS_PY 4096
#define WS_JS 6144
#define WS_PK 8192

// ---------------- K1: Z, px_num, py_num partials (input only) -------------
__global__ __launch_bounds__(NTHR, 8) void pass1_kernel(
    const float* __restrict__ inp, float* __restrict__ ws)
{
    const int part = blockIdx.x;
    const float4* __restrict__ in4 =
        (const float4*)(inp + (size_t)part * PIX_PART);
    const int tid = threadIdx.x;
    const int pix0 = (part & (PARTS - 1)) * PIX_PART;
    const float cs = 1.0f / 256.0f;

    float s = 0.f, pxn = 0.f, pyn = 0.f;
#pragma unroll
    for (int h = 0; h < 2; ++h) {
        float4 x[4];
#pragma unroll
        for (int i = 0; i < 4; ++i) x[i] = in4[(h * 4 + i) * NTHR + tid];
#pragma unroll
        for (int i = 0; i < 4; ++i) {
            const int gp = pix0 + ((h * 4 + i) * NTHR + tid) * 4;
            const float yh  = ((float)(gp >> 8) + 1.f - 128.f) * cs;
            const float xw0 = ((float)(gp & 255) + 1.f - 128.f) * cs;
            const float e0 = __expf(x[i].x), e1 = __expf(x[i].y);
            const float e2 = __expf(x[i].z), e3 = __expf(x[i].w);
            s   += (e0 + e1) + (e2 + e3);
            pxn += e0 * xw0 + e1 * (xw0 + cs) + e2 * (xw0 + 2.f * cs)
                 + e3 * (xw0 + 3.f * cs);
            pyn += ((e0 + e1) + (e2 + e3)) * yh;
        }
    }
#pragma unroll
    for (int off = 1; off < 64; off <<= 1) {
        s   += __shfl_xor(s, off);
        pxn += __shfl_xor(pxn, off);
        pyn += __shfl_xor(pyn, off);
    }
    __shared__ float ls[4], lx[4], ly[4];
    const int wid = tid >> 6, lane = tid & 63;
    if (lane == 0) { ls[wid] = s; lx[wid] = pxn; ly[wid] = pyn; }
    __syncthreads();
    if (tid == 0) {
        ws[WS_Z  + part] = (ls[0] + ls[1]) + (ls[2] + ls[3]);
        ws[WS_PX + part] = (lx[0] + lx[1]) + (lx[2] + lx[3]);
        ws[WS_PY + part] = (ly[0] + ly[1]) + (ly[2] + ly[3]);
    }
}

// ---------------- K2: jsd + argmax(target) --------------------------------
__global__ __launch_bounds__(NTHR, 8) void pass2_kernel(
    const float* __restrict__ inp, const float* __restrict__ tgt,
    float* __restrict__ ws)
{
    const int part = blockIdx.x;
    const int hm = part >> 3;
    const int tid = threadIdx.x;

    float Z = 0.f;
#pragma unroll
    for (int i = 0; i < PARTS; ++i) Z += ws[WS_Z + hm * PARTS + i];
    const float hInvZ = 0.5f / Z;

    const size_t base = (size_t)part * PIX_PART;
    const float4* __restrict__ in4 = (const float4*)(inp + base);
    const float4* __restrict__ tg4 = (const float4*)(tgt + base);
    const int pix0 = (part & (PARTS - 1)) * PIX_PART;

    float jsd = 0.f;   // sum m*(log(m) - m)
    unsigned long long best = 0ull;
#pragma unroll
    for (int h = 0; h < 2; ++h) {
        float4 x[4], t[4];
#pragma unroll
        for (int i = 0; i < 4; ++i) {
            const int f4 = (h * 4 + i) * NTHR + tid;
            x[i] = in4[f4];
            t[i] = tg4[f4];
        }
#pragma unroll
        for (int i = 0; i < 4; ++i) {
            const int gp = pix0 + ((h * 4 + i) * NTHR + tid) * 4;
            const float m0 = fmaf(__expf(x[i].x), hInvZ, 0.5f * t[i].x);
            const float m1 = fmaf(__expf(x[i].y), hInvZ, 0.5f * t[i].y);
            const float m2 = fmaf(__expf(x[i].z), hInvZ, 0.5f * t[i].z);
            const float m3 = fmaf(__expf(x[i].w), hInvZ, 0.5f * t[i].w);
            jsd += m0 * (__logf(m0) - m0) + m1 * (__logf(m1) - m1)
                 + m2 * (__logf(m2) - m2) + m3 * (__logf(m3) - m3);

            // first-occurrence argmax: pack (valbits<<32)|(65535-idx), max
            const unsigned long long k0 =
                ((unsigned long long)__float_as_uint(t[i].x) << 32) | (unsigned)(65535 - gp);
            const unsigned long long k1 =
                ((unsigned long long)__float_as_uint(t[i].y) << 32) | (unsigned)(65534 - gp);
            const unsigned long long k2 =
                ((unsigned long long)__float_as_uint(t[i].z) << 32) | (unsigned)(65533 - gp);
            const unsigned long long k3 =
                ((unsigned long long)__float_as_uint(t[i].w) << 32) | (unsigned)(65532 - gp);
            unsigned long long ka = k0 > k1 ? k0 : k1;
            unsigned long long kb = k2 > k3 ? k2 : k3;
            ka = ka > kb ? ka : kb;
            best = best > ka ? best : ka;
        }
    }

#pragma unroll
    for (int off = 1; off < 64; off <<= 1) {
        jsd += __shfl_xor(jsd, off);
        const unsigned long long b2 = __shfl_xor(best, off);
        best = best > b2 ? best : b2;
    }
    __shared__ float ljs[4];
    __shared__ unsigned long long lbk[4];
    const int wid = tid >> 6, lane = tid & 63;
    if (lane == 0) { ljs[wid] = jsd; lbk[wid] = best; }
    __syncthreads();
    if (tid == 0) {
        float JS = 0.f;
        unsigned long long BK = 0ull;
#pragma unroll
        for (int i = 0; i < 4; ++i) {
            JS += ljs[i];
            BK = BK > lbk[i] ? BK : lbk[i];
        }
        ws[WS_JS + part] = JS;
        ((unsigned long long*)(ws + WS_PK))[part] = BK;
    }
}

// ---------------- K3: finalize --------------------------------------------
__global__ __launch_bounds__(256) void finalize_kernel(
    const float* __restrict__ ws, float* __restrict__ out)
{
    const int t = threadIdx.x; // heatmap id
    const unsigned long long* packp = (const unsigned long long*)(ws + WS_PK);

    float Z = 0.f, PXN = 0.f, PYN = 0.f, JS = 0.f;
    unsigned long long BK = 0ull;
#pragma unroll
    for (int i = 0; i < PARTS; ++i) {
        Z   += ws[WS_Z  + t * PARTS + i];
        PXN += ws[WS_PX + t * PARTS + i];
        PYN += ws[WS_PY + t * PARTS + i];
        JS  += ws[WS_JS + t * PARTS + i];
        const unsigned long long b = packp[t * PARTS + i];
        BK = BK > b ? BK : b;
    }
    const float invZ = 1.0f / Z;
    const float PX = PXN * invZ, PY = PYN * invZ;
    JS *= (1.0f / (float)HM_N);
    const int gp = 65535 - (int)(BK & 0xFFFFFFFFull);
    const float tx = ((float)(gp & 255) + 1.f - 128.f) * (1.0f / 256.0f);
    const float ty = ((float)(gp >> 8)  + 1.f - 128.f) * (1.0f / 256.0f);

    const float ex = tx - PX, ey = ty - PY;
    float v = sqrtf(ex * ex + ey * ey) + JS;

    __shared__ float sPX[256], sPY[256], sTX[256], sTY[256], acc[256];
    sPX[t] = PX; sPY[t] = PY; sTX[t] = tx; sTY[t] = ty;
    __syncthreads();

    if (t < 128) { // inter-landmark distance term (channels 0,1)
        const int a = 2 * t, b = 2 * t + 1;
        const float pdx = sPX[a] - sPX[b], pdy = sPY[a] - sPY[b];
        const float pd  = sqrtf(pdx * pdx + pdy * pdy);
        const float tdx = sTX[a] - sTX[b], tdy = sTY[a] - sTY[b];
        const float td  = sqrtf(tdx * tdx + tdy * tdy);
        v += fabsf(pd - td) / td;
    }
    acc[t] = v;
    __syncthreads();
#pragma unroll
    for (int off = 128; off > 0; off >>= 1) {
        if (t < off) acc[t] += acc[t + off];
        __syncthreads();
    }
    if (t == 0) out[0] = acc[0] * (1.0f / 128.0f);
}

extern "C" void kernel_launch(void* const* d_in, const int* in_sizes, int n_in,
                              void* d_out, int out_size, void* d_ws, size_t ws_size,
                              hipStream_t stream) {
    const float* inp = (const float*)d_in[0];
    const float* tgt = (const float*)d_in[1];
    float* out = (float*)d_out;
    float* ws  = (float*)d_ws;

    pass1_kernel<<<NPART, NTHR, 0, stream>>>(inp, ws);
    pass2_kernel<<<NPART, NTHR, 0, stream>>>(inp, tgt, ws);
    finalize_kernel<<<1, 256, 0, stream>>>(ws, out);
}